// Round 8
// baseline (464.221 us; speedup 1.0000x reference)
//
#include <hip/hip_runtime.h>
#include <hip/hip_bf16.h>

// DEChannelPool: 6 soft-morphology branches + per-channel BN + 1x1 conv + BN + ReLU.
// Inputs fp32, output fp32.
// exp(beta*(w±x)) = exp(beta*w)*exp(±beta*x); BN+conv fold to alpha*log(S)+const,
// const cancels in final scalar BN.
// R8: amortize staging latency -- pass1 = 8 ch/block dbuf LDS (2304 blocks);
// pass2 = 16 ch/block, 4 px/thread, distributed atomicAdd into ye/yd;
// k_wexp folded into k_exp; 8 dispatches. Zero hot atomics (R5 lesson);
// VGPR kept ~60 (R4 lesson).

#define BETA 15.0f
#define MSHIFT 25.0f
#define INV_BETA (1.0f/15.0f)
#define EPSB 1e-5f
#define Hn 192
#define Wn 192
#define HWn (192*192)
#define N1 (8*192*192)
#define SFLOOR 1e-37f

// workspace layout (4-byte units)
#define WS_SCAL  0
#define WS_YE    4
#define WS_YD    294916
#define WS_SUM   589828
#define WS_SQS   590212
#define WS_ALPHA 590596
#define WS_WG    590980
#define WS_PART  594436                 // 768 rows x 1152 cols
#define WS_EF    1479172                // u32; 512*36864 -> end 20353540 (81.4 MB)

__device__ __forceinline__ unsigned packbf(float a, float b) {
    union { __hip_bfloat16 h; unsigned short s; } ua, ub;
    ua.h = __float2bfloat16(a); ub.h = __float2bfloat16(b);
    return (unsigned)ua.s | ((unsigned)ub.s << 16);
}
__device__ __forceinline__ float2 unpackbf(unsigned u) {
    return make_float2(__uint_as_float(u << 16), __uint_as_float(u & 0xffff0000u));
}

// exp-field + (for first 3456 threads) weight-exp table
__global__ __launch_bounds__(256) void k_exp(const float* __restrict__ x,
                                             unsigned* __restrict__ ef,
                                             const float* __restrict__ we,
                                             const float* __restrict__ wd,
                                             float* __restrict__ wg) {
    size_t i = (size_t)blockIdx.x * 256 + threadIdx.x;   // covers 512*HWn exactly
    float bx = BETA * x[i];
    ef[i] = packbf(__expf(-bx - MSHIFT), __expf(bx - MSHIFT));
    if (i < 3456) {
        int kb = (int)i / 576, rem = (int)i - kb * 576;
        float w = (kb < 3) ? we[kb * 576 + rem] : wd[(kb - 3) * 576 + rem];
        wg[i] = __expf(BETA * w);
    }
}

// stage 38 rows x 38 cols (tile 32x32 + halo 3) into float2 LDS (row stride 39)
__device__ __forceinline__ void stage38(float2* E, const unsigned* __restrict__ plane,
                                        int h0, int w0, int tid, unsigned p0) {
    const int row = tid >> 5, col = tid & 31;
#pragma unroll
    for (int rr = 0; rr < 5; ++rr) {
        int r = row + rr * 8;
        if (r < 38) {
            int gh = h0 - 3 + r;
            bool rok = ((unsigned)gh < (unsigned)Hn);
            int ghc = min(max(gh, 0), Hn - 1);
            {
                int gw = w0 - 3 + col;
                int gwc = min(max(gw, 0), Wn - 1);
                unsigned u = plane[ghc * Wn + gwc];
                bool ok = rok && ((unsigned)gw < (unsigned)Wn);
                E[r * 39 + col] = unpackbf(ok ? u : p0);
            }
            if (col < 6) {
                int gw = w0 + 29 + col;
                int gwc = min(max(gw, 0), Wn - 1);
                unsigned u = plane[ghc * Wn + gwc];
                bool ok = rok && ((unsigned)gw < (unsigned)Wn);
                E[r * 39 + col + 32] = unpackbf(ok ? u : p0);
            }
        }
    }
}

// pass 1: 8 channels per block, double-buffered staging, per-wave partial stats
__global__ __launch_bounds__(256) void k_morph8(
    const unsigned* __restrict__ ef, const float* __restrict__ wg,
    float* __restrict__ part) {
    __shared__ float2 EB[2][38 * 39];
    const int tid = threadIdx.x;
    const int t = blockIdx.x;                 // 36 tiles
    const int b = blockIdx.y >> 3, cg = blockIdx.y & 7;
    const int h0 = (t / 6) * 32, w0 = (t % 6) * 32;
    const int c0 = cg * 8;
    const unsigned p0 = packbf(__expf(-MSHIFT), __expf(-MSHIFT));
    const int px3 = (tid & 31) + 3;
    const int r0 = (tid >> 5) * 4;
    const int lane = tid & 63, wv = tid >> 6;
    const int col = (b * 36 + t) * 4 + wv;

    const unsigned* base = ef + (size_t)(b * 64 + c0) * HWn;
    stage38(EB[0], base, h0, w0, tid, p0);
    __syncthreads();

    for (int ci = 0; ci < 8; ++ci) {
        const int c = c0 + ci;
        const float2* E = EB[ci & 1];
        if (ci < 7)
            stage38(EB[(ci + 1) & 1], base + (size_t)(ci + 1) * HWn, h0, w0, tid, p0);
        float s[6] = {0,0,0,0,0,0}, q[6] = {0,0,0,0,0,0};
#pragma unroll
        for (int br = 0; br < 3; ++br) {
            const int d = br + 1, nr = 4 + 2 * d;
            float SEa[4] = {0,0,0,0}, SDa[4] = {0,0,0,0};
#pragma unroll
            for (int j = 0; j < 3; ++j) {
                float WE3[3], WD3[3];
#pragma unroll
                for (int i = 0; i < 3; ++i) {
                    WE3[i] = wg[(br * 64 + c) * 9 + i * 3 + j];
                    WD3[i] = wg[((br + 3) * 64 + c) * 9 + i * 3 + j];
                }
                float2 cv[10];
#pragma unroll
                for (int r = 0; r < nr; ++r)
                    cv[r] = E[(r0 + 3 - d + r) * 39 + px3 + (j - 1) * d];
#pragma unroll
                for (int k = 0; k < 4; ++k)
#pragma unroll
                    for (int i = 0; i < 3; ++i) {
                        SEa[k] = fmaf(WE3[i], cv[k + i * d].x, SEa[k]);
                        SDa[k] = fmaf(WD3[i], cv[k + i * d].y, SDa[k]);
                    }
            }
#pragma unroll
            for (int k = 0; k < 4; ++k) {
                float me = -(__logf(fmaxf(SEa[k], SFLOOR)) + MSHIFT) * INV_BETA;
                float md =  (__logf(fmaxf(SDa[k], SFLOOR)) + MSHIFT) * INV_BETA;
                s[br]     += me; q[br]     = fmaf(me, me, q[br]);
                s[br + 3] += md; q[br + 3] = fmaf(md, md, q[br + 3]);
            }
        }
#pragma unroll
        for (int v = 0; v < 6; ++v) {
            float a = s[v], b2 = q[v];
#pragma unroll
            for (int off = 32; off; off >>= 1) {
                a  += __shfl_down(a, off, 64);
                b2 += __shfl_down(b2, off, 64);
            }
            if (lane == 0) {
                part[(size_t)(v * 64 + c) * 1152 + col] = a;
                part[(size_t)((6 + v) * 64 + c) * 1152 + col] = b2;
            }
        }
        __syncthreads();
    }
}

__global__ __launch_bounds__(256) void k_red(const float* __restrict__ part,
                                             float* __restrict__ sums) {
    const int w = blockIdx.x * 4 + (threadIdx.x >> 6);   // 0..767
    const int lane = threadIdx.x & 63;
    const float* src = part + (size_t)w * 1152;
    float a = 0.f;
    for (int i = lane; i < 1152; i += 64) a += src[i];
#pragma unroll
    for (int off = 32; off; off >>= 1) a += __shfl_down(a, off, 64);
    if (lane == 0) sums[w] = a;
}

__global__ void k_alpha(const float* __restrict__ sum, const float* __restrict__ sqs,
                        const float* __restrict__ bn_ge,
                        const float* __restrict__ bn_gd,
                        const float* __restrict__ conve,
                        const float* __restrict__ convd,
                        float* __restrict__ alpha) {
    int tid = threadIdx.x;
    if (tid >= 384) return;
    float mean = sum[tid] * (1.0f / N1);
    float var  = sqs[tid] * (1.0f / N1) - mean * mean;
    float inv  = rsqrtf(fmaxf(var, 0.f) + EPSB);
    float g, cw, sgn;
    if (tid < 192) { g = bn_ge[tid];       cw = conve[tid];       sgn = -1.f; }
    else           { g = bn_gd[tid - 192]; cw = convd[tid - 192]; sgn =  1.f; }
    alpha[tid] = sgn * cw * g * inv * INV_BETA;
}

// pass 2: 16 channels per block, 4 px/thread, distributed atomicAdd into ye/yd
__global__ __launch_bounds__(256) void k_reduce16(
    const unsigned* __restrict__ ef, const float* __restrict__ wg,
    const float* __restrict__ alpha,
    float* __restrict__ ye, float* __restrict__ yd) {
    __shared__ float2 EB[2][38 * 39];
    const int tid = threadIdx.x;
    const int t = blockIdx.x;                 // 36 tiles
    const int bz = blockIdx.y;                // b*4 + cg
    const int b = bz >> 2, cg = bz & 3;
    const int h0 = (t / 6) * 32, w0 = (t % 6) * 32;
    const int c0 = cg * 16;
    const unsigned p0 = packbf(__expf(-MSHIFT), __expf(-MSHIFT));
    const int px3 = (tid & 31) + 3;
    const int r0 = (tid >> 5) * 4;
    float accE[4] = {0,0,0,0}, accD[4] = {0,0,0,0};

    const unsigned* base = ef + (size_t)(b * 64 + c0) * HWn;
    stage38(EB[0], base, h0, w0, tid, p0);
    __syncthreads();

    for (int ci = 0; ci < 16; ++ci) {
        const int c = c0 + ci;
        const float2* E = EB[ci & 1];
        if (ci < 15)
            stage38(EB[(ci + 1) & 1], base + (size_t)(ci + 1) * HWn, h0, w0, tid, p0);
#pragma unroll
        for (int br = 0; br < 3; ++br) {
            const int d = br + 1, nr = 4 + 2 * d;
            const float aE = alpha[br * 64 + c];
            const float aD = alpha[(br + 3) * 64 + c];
            float SEa[4] = {0,0,0,0}, SDa[4] = {0,0,0,0};
#pragma unroll
            for (int j = 0; j < 3; ++j) {
                float WE3[3], WD3[3];
#pragma unroll
                for (int i = 0; i < 3; ++i) {
                    WE3[i] = wg[(br * 64 + c) * 9 + i * 3 + j];
                    WD3[i] = wg[((br + 3) * 64 + c) * 9 + i * 3 + j];
                }
                float2 cv[10];
#pragma unroll
                for (int r = 0; r < nr; ++r)
                    cv[r] = E[(r0 + 3 - d + r) * 39 + px3 + (j - 1) * d];
#pragma unroll
                for (int k = 0; k < 4; ++k)
#pragma unroll
                    for (int i = 0; i < 3; ++i) {
                        SEa[k] = fmaf(WE3[i], cv[k + i * d].x, SEa[k]);
                        SDa[k] = fmaf(WD3[i], cv[k + i * d].y, SDa[k]);
                    }
            }
#pragma unroll
            for (int k = 0; k < 4; ++k) {
                accE[k] = fmaf(aE, __logf(fmaxf(SEa[k], SFLOOR)), accE[k]);
                accD[k] = fmaf(aD, __logf(fmaxf(SDa[k], SFLOOR)), accD[k]);
            }
        }
        __syncthreads();
    }
#pragma unroll
    for (int k = 0; k < 4; ++k) {
        int idx = b * HWn + (h0 + r0 + k) * Wn + (w0 + px3 - 3);
        atomicAdd(&ye[idx], accE[k]);
        atomicAdd(&yd[idx], accD[k]);
    }
}

__global__ __launch_bounds__(256) void k_fstats(const float* __restrict__ ye,
                                                const float* __restrict__ yd,
                                                float* __restrict__ scal) {
    int i = blockIdx.x * 256 + threadIdx.x;
    float a = ye[i], b = yd[i];
    float v[4] = {a, a * a, b, b * b};
    __shared__ float red[4][4];
    int lane = threadIdx.x & 63, wv = threadIdx.x >> 6;
#pragma unroll
    for (int k = 0; k < 4; ++k) {
        float tv = v[k];
#pragma unroll
        for (int off = 32; off; off >>= 1) tv += __shfl_down(tv, off, 64);
        if (lane == 0) red[wv][k] = tv;
    }
    __syncthreads();
    if (threadIdx.x < 4)
        atomicAdd(&scal[threadIdx.x],
                  red[0][threadIdx.x] + red[1][threadIdx.x] + red[2][threadIdx.x] + red[3][threadIdx.x]);
}

__global__ __launch_bounds__(256) void k_final(
    const float* __restrict__ ye, const float* __restrict__ yd,
    const float* __restrict__ scal,
    const float* __restrict__ g_e, const float* __restrict__ b_e,
    const float* __restrict__ g_d, const float* __restrict__ b_d,
    float* __restrict__ out) {
    int i = blockIdx.x * 256 + threadIdx.x;
    float me_ = scal[0] * (1.0f / N1);
    float ve  = scal[1] * (1.0f / N1) - me_ * me_;
    float ie  = rsqrtf(fmaxf(ve, 0.f) + EPSB);
    float md_ = scal[2] * (1.0f / N1);
    float vd  = scal[3] * (1.0f / N1) - md_ * md_;
    float idv = rsqrtf(fmaxf(vd, 0.f) + EPSB);
    float ge = g_e[0], be = b_e[0];
    float gd = g_d[0], bd = b_d[0];
    int b = i / HWn, rem = i - b * HWn;
    float oe = fmaxf(ge * (ye[i] - me_) * ie + be, 0.f);
    float od = fmaxf(gd * (yd[i] - md_) * idv + bd, 0.f);
    out[(size_t)(b * 2) * HWn + rem]     = oe;
    out[(size_t)(b * 2 + 1) * HWn + rem] = od;
}

extern "C" void kernel_launch(void* const* d_in, const int* in_sizes, int n_in,
                              void* d_out, int out_size, void* d_ws, size_t ws_size,
                              hipStream_t stream) {
    const float* x     = (const float*)d_in[0];
    const float* we    = (const float*)d_in[1];
    const float* wd    = (const float*)d_in[2];
    const float* bn_ge = (const float*)d_in[3];
    const float* bn_gd = (const float*)d_in[5];
    const float* conve = (const float*)d_in[7];
    const float* convd = (const float*)d_in[8];
    const float* g_e   = (const float*)d_in[9];
    const float* b_e   = (const float*)d_in[10];
    const float* g_d   = (const float*)d_in[11];
    const float* b_d   = (const float*)d_in[12];
    float* ws = (float*)d_ws;
    unsigned* ef = (unsigned*)d_ws + WS_EF;

    // zero scal + ye + yd (contiguous at ws start)
    hipMemsetAsync(d_ws, 0, (size_t)(4 + 2 * N1) * sizeof(float), stream);
    hipLaunchKernelGGL(k_exp, dim3(512 * HWn / 256), dim3(256), 0, stream,
                       x, ef, we, wd, ws + WS_WG);
    hipLaunchKernelGGL(k_morph8, dim3(36, 64), dim3(256), 0, stream,
                       ef, ws + WS_WG, ws + WS_PART);
    hipLaunchKernelGGL(k_red, dim3(192), dim3(256), 0, stream, ws + WS_PART, ws + WS_SUM);
    hipLaunchKernelGGL(k_alpha, dim3(1), dim3(384), 0, stream,
                       ws + WS_SUM, ws + WS_SQS, bn_ge, bn_gd, conve, convd, ws + WS_ALPHA);
    hipLaunchKernelGGL(k_reduce16, dim3(36, 32), dim3(256), 0, stream,
                       ef, ws + WS_WG, ws + WS_ALPHA, ws + WS_YE, ws + WS_YD);
    hipLaunchKernelGGL(k_fstats, dim3(1152), dim3(256), 0, stream,
                       ws + WS_YE, ws + WS_YD, ws + WS_SCAL);
    hipLaunchKernelGGL(k_final, dim3(1152), dim3(256), 0, stream,
                       ws + WS_YE, ws + WS_YD, ws + WS_SCAL, g_e, b_e, g_d, b_d,
                       (float*)d_out);
}

// Round 9
// 441.207 us; speedup vs baseline: 1.0522x; 1.0522x over previous
//
#include <hip/hip_runtime.h>
#include <hip/hip_bf16.h>

// DEChannelPool: 6 soft-morphology branches + per-channel BN + 1x1 conv + BN + ReLU.
// Inputs fp32, output fp32.
// exp(beta*(w±x)) = exp(beta*w)*exp(±beta*x); BN+conv fold to alpha*log(S)+const,
// const cancels in final scalar BN.
// R9: keep R8 pass1 (measured 166us). Pass2 rebuilt as pass1's mirror: 38-row
// single-buffer LDS (12KB), 8 ch/block, 4 px/thread, alpha computed in-block
// (k_alpha dispatch removed), distributed atomics into ye/yd. 7 dispatches.

#define BETA 15.0f
#define MSHIFT 25.0f
#define INV_BETA (1.0f/15.0f)
#define EPSB 1e-5f
#define Hn 192
#define Wn 192
#define HWn (192*192)
#define N1 (8*192*192)
#define SFLOOR 1e-37f

// workspace layout (4-byte units)
#define WS_SCAL  0
#define WS_YE    4
#define WS_YD    294916
#define WS_SUM   589828
#define WS_SQS   590212
#define WS_WG    590980
#define WS_PART  594436                 // 768 rows x 1152 cols
#define WS_EF    1479172                // u32; 512*36864 -> end 20353540 (81.4 MB)

__device__ __forceinline__ unsigned packbf(float a, float b) {
    union { __hip_bfloat16 h; unsigned short s; } ua, ub;
    ua.h = __float2bfloat16(a); ub.h = __float2bfloat16(b);
    return (unsigned)ua.s | ((unsigned)ub.s << 16);
}
__device__ __forceinline__ float2 unpackbf(unsigned u) {
    return make_float2(__uint_as_float(u << 16), __uint_as_float(u & 0xffff0000u));
}

// exp-field + (for first 3456 threads) weight-exp table
__global__ __launch_bounds__(256) void k_exp(const float* __restrict__ x,
                                             unsigned* __restrict__ ef,
                                             const float* __restrict__ we,
                                             const float* __restrict__ wd,
                                             float* __restrict__ wg) {
    size_t i = (size_t)blockIdx.x * 256 + threadIdx.x;   // covers 512*HWn exactly
    float bx = BETA * x[i];
    ef[i] = packbf(__expf(-bx - MSHIFT), __expf(bx - MSHIFT));
    if (i < 3456) {
        int kb = (int)i / 576, rem = (int)i - kb * 576;
        float w = (kb < 3) ? we[kb * 576 + rem] : wd[(kb - 3) * 576 + rem];
        wg[i] = __expf(BETA * w);
    }
}

// stage 38 rows x 38 cols (tile 32x32 + halo 3) into float2 LDS (row stride 39)
__device__ __forceinline__ void stage38(float2* E, const unsigned* __restrict__ plane,
                                        int h0, int w0, int tid, unsigned p0) {
    const int row = tid >> 5, col = tid & 31;
#pragma unroll
    for (int rr = 0; rr < 5; ++rr) {
        int r = row + rr * 8;
        if (r < 38) {
            int gh = h0 - 3 + r;
            bool rok = ((unsigned)gh < (unsigned)Hn);
            int ghc = min(max(gh, 0), Hn - 1);
            {
                int gw = w0 - 3 + col;
                int gwc = min(max(gw, 0), Wn - 1);
                unsigned u = plane[ghc * Wn + gwc];
                bool ok = rok && ((unsigned)gw < (unsigned)Wn);
                E[r * 39 + col] = unpackbf(ok ? u : p0);
            }
            if (col < 6) {
                int gw = w0 + 29 + col;
                int gwc = min(max(gw, 0), Wn - 1);
                unsigned u = plane[ghc * Wn + gwc];
                bool ok = rok && ((unsigned)gw < (unsigned)Wn);
                E[r * 39 + col + 32] = unpackbf(ok ? u : p0);
            }
        }
    }
}

// pass 1: 8 channels per block, double-buffered staging, per-wave partial stats
__global__ __launch_bounds__(256) void k_morph8(
    const unsigned* __restrict__ ef, const float* __restrict__ wg,
    float* __restrict__ part) {
    __shared__ float2 EB[2][38 * 39];
    const int tid = threadIdx.x;
    const int t = blockIdx.x;                 // 36 tiles
    const int b = blockIdx.y >> 3, cg = blockIdx.y & 7;
    const int h0 = (t / 6) * 32, w0 = (t % 6) * 32;
    const int c0 = cg * 8;
    const unsigned p0 = packbf(__expf(-MSHIFT), __expf(-MSHIFT));
    const int px3 = (tid & 31) + 3;
    const int r0 = (tid >> 5) * 4;
    const int lane = tid & 63, wv = tid >> 6;
    const int col = (b * 36 + t) * 4 + wv;

    const unsigned* base = ef + (size_t)(b * 64 + c0) * HWn;
    stage38(EB[0], base, h0, w0, tid, p0);
    __syncthreads();

    for (int ci = 0; ci < 8; ++ci) {
        const int c = c0 + ci;
        const float2* E = EB[ci & 1];
        if (ci < 7)
            stage38(EB[(ci + 1) & 1], base + (size_t)(ci + 1) * HWn, h0, w0, tid, p0);
        float s[6] = {0,0,0,0,0,0}, q[6] = {0,0,0,0,0,0};
#pragma unroll
        for (int br = 0; br < 3; ++br) {
            const int d = br + 1, nr = 4 + 2 * d;
            float SEa[4] = {0,0,0,0}, SDa[4] = {0,0,0,0};
#pragma unroll
            for (int j = 0; j < 3; ++j) {
                float WE3[3], WD3[3];
#pragma unroll
                for (int i = 0; i < 3; ++i) {
                    WE3[i] = wg[(br * 64 + c) * 9 + i * 3 + j];
                    WD3[i] = wg[((br + 3) * 64 + c) * 9 + i * 3 + j];
                }
                float2 cv[10];
#pragma unroll
                for (int r = 0; r < nr; ++r)
                    cv[r] = E[(r0 + 3 - d + r) * 39 + px3 + (j - 1) * d];
#pragma unroll
                for (int k = 0; k < 4; ++k)
#pragma unroll
                    for (int i = 0; i < 3; ++i) {
                        SEa[k] = fmaf(WE3[i], cv[k + i * d].x, SEa[k]);
                        SDa[k] = fmaf(WD3[i], cv[k + i * d].y, SDa[k]);
                    }
            }
#pragma unroll
            for (int k = 0; k < 4; ++k) {
                float me = -(__logf(fmaxf(SEa[k], SFLOOR)) + MSHIFT) * INV_BETA;
                float md =  (__logf(fmaxf(SDa[k], SFLOOR)) + MSHIFT) * INV_BETA;
                s[br]     += me; q[br]     = fmaf(me, me, q[br]);
                s[br + 3] += md; q[br + 3] = fmaf(md, md, q[br + 3]);
            }
        }
#pragma unroll
        for (int v = 0; v < 6; ++v) {
            float a = s[v], b2 = q[v];
#pragma unroll
            for (int off = 32; off; off >>= 1) {
                a  += __shfl_down(a, off, 64);
                b2 += __shfl_down(b2, off, 64);
            }
            if (lane == 0) {
                part[(size_t)(v * 64 + c) * 1152 + col] = a;
                part[(size_t)((6 + v) * 64 + c) * 1152 + col] = b2;
            }
        }
        __syncthreads();
    }
}

__global__ __launch_bounds__(256) void k_red(const float* __restrict__ part,
                                             float* __restrict__ sums) {
    const int w = blockIdx.x * 4 + (threadIdx.x >> 6);   // 0..767
    const int lane = threadIdx.x & 63;
    const float* src = part + (size_t)w * 1152;
    float a = 0.f;
    for (int i = lane; i < 1152; i += 64) a += src[i];
#pragma unroll
    for (int off = 32; off; off >>= 1) a += __shfl_down(a, off, 64);
    if (lane == 0) sums[w] = a;
}

// pass 2: 8 channels per block, single 38-row buffer, in-block alpha, atomics out
__global__ __launch_bounds__(256) void k_pass2(
    const unsigned* __restrict__ ef, const float* __restrict__ wg,
    const float* __restrict__ sum, const float* __restrict__ sqs,
    const float* __restrict__ bn_ge, const float* __restrict__ bn_gd,
    const float* __restrict__ conve, const float* __restrict__ convd,
    float* __restrict__ ye, float* __restrict__ yd) {
    __shared__ float2 E[38 * 39];
    __shared__ float aL[48];
    const int tid = threadIdx.x;
    const int t = blockIdx.x;                 // 36 tiles
    const int b = blockIdx.y >> 3, cg = blockIdx.y & 7;
    const int h0 = (t / 6) * 32, w0 = (t % 6) * 32;
    const int c0 = cg * 8;
    const unsigned p0 = packbf(__expf(-MSHIFT), __expf(-MSHIFT));
    const int px3 = (tid & 31) + 3;
    const int r0 = (tid >> 5) * 4;
    float accE[4] = {0,0,0,0}, accD[4] = {0,0,0,0};

    // alpha for this block's 6 branches x 8 channels
    if (tid < 48) {
        int v = tid >> 3, ci = tid & 7;
        int gi = v * 64 + c0 + ci;
        float mean = sum[gi] * (1.0f / N1);
        float var  = sqs[gi] * (1.0f / N1) - mean * mean;
        float inv  = rsqrtf(fmaxf(var, 0.f) + EPSB);
        float g, cw, sgn;
        if (v < 3) { g = bn_ge[gi];       cw = conve[gi];       sgn = -1.f; }
        else       { g = bn_gd[gi - 192]; cw = convd[gi - 192]; sgn =  1.f; }
        aL[tid] = sgn * cw * g * inv * INV_BETA;
    }

    const unsigned* base = ef + (size_t)(b * 64 + c0) * HWn;
    for (int ci = 0; ci < 8; ++ci) {
        const int c = c0 + ci;
        __syncthreads();
        stage38(E, base + (size_t)ci * HWn, h0, w0, tid, p0);
        __syncthreads();
#pragma unroll
        for (int br = 0; br < 3; ++br) {
            const int d = br + 1, nr = 4 + 2 * d;
            const float aE = aL[br * 8 + ci];
            const float aD = aL[(br + 3) * 8 + ci];
            float SEa[4] = {0,0,0,0}, SDa[4] = {0,0,0,0};
#pragma unroll
            for (int j = 0; j < 3; ++j) {
                float WE3[3], WD3[3];
#pragma unroll
                for (int i = 0; i < 3; ++i) {
                    WE3[i] = wg[(br * 64 + c) * 9 + i * 3 + j];
                    WD3[i] = wg[((br + 3) * 64 + c) * 9 + i * 3 + j];
                }
                float2 cv[10];
#pragma unroll
                for (int r = 0; r < nr; ++r)
                    cv[r] = E[(r0 + 3 - d + r) * 39 + px3 + (j - 1) * d];
#pragma unroll
                for (int k = 0; k < 4; ++k)
#pragma unroll
                    for (int i = 0; i < 3; ++i) {
                        SEa[k] = fmaf(WE3[i], cv[k + i * d].x, SEa[k]);
                        SDa[k] = fmaf(WD3[i], cv[k + i * d].y, SDa[k]);
                    }
            }
#pragma unroll
            for (int k = 0; k < 4; ++k) {
                accE[k] = fmaf(aE, __logf(fmaxf(SEa[k], SFLOOR)), accE[k]);
                accD[k] = fmaf(aD, __logf(fmaxf(SDa[k], SFLOOR)), accD[k]);
            }
        }
    }
#pragma unroll
    for (int k = 0; k < 4; ++k) {
        int idx = b * HWn + (h0 + r0 + k) * Wn + (w0 + px3 - 3);
        atomicAdd(&ye[idx], accE[k]);
        atomicAdd(&yd[idx], accD[k]);
    }
}

__global__ __launch_bounds__(256) void k_fstats(const float* __restrict__ ye,
                                                const float* __restrict__ yd,
                                                float* __restrict__ scal) {
    int i = blockIdx.x * 256 + threadIdx.x;
    float a = ye[i], b = yd[i];
    float v[4] = {a, a * a, b, b * b};
    __shared__ float red[4][4];
    int lane = threadIdx.x & 63, wv = threadIdx.x >> 6;
#pragma unroll
    for (int k = 0; k < 4; ++k) {
        float tv = v[k];
#pragma unroll
        for (int off = 32; off; off >>= 1) tv += __shfl_down(tv, off, 64);
        if (lane == 0) red[wv][k] = tv;
    }
    __syncthreads();
    if (threadIdx.x < 4)
        atomicAdd(&scal[threadIdx.x],
                  red[0][threadIdx.x] + red[1][threadIdx.x] + red[2][threadIdx.x] + red[3][threadIdx.x]);
}

__global__ __launch_bounds__(256) void k_final(
    const float* __restrict__ ye, const float* __restrict__ yd,
    const float* __restrict__ scal,
    const float* __restrict__ g_e, const float* __restrict__ b_e,
    const float* __restrict__ g_d, const float* __restrict__ b_d,
    float* __restrict__ out) {
    int i = blockIdx.x * 256 + threadIdx.x;
    float me_ = scal[0] * (1.0f / N1);
    float ve  = scal[1] * (1.0f / N1) - me_ * me_;
    float ie  = rsqrtf(fmaxf(ve, 0.f) + EPSB);
    float md_ = scal[2] * (1.0f / N1);
    float vd  = scal[3] * (1.0f / N1) - md_ * md_;
    float idv = rsqrtf(fmaxf(vd, 0.f) + EPSB);
    float ge = g_e[0], be = b_e[0];
    float gd = g_d[0], bd = b_d[0];
    int b = i / HWn, rem = i - b * HWn;
    float oe = fmaxf(ge * (ye[i] - me_) * ie + be, 0.f);
    float od = fmaxf(gd * (yd[i] - md_) * idv + bd, 0.f);
    out[(size_t)(b * 2) * HWn + rem]     = oe;
    out[(size_t)(b * 2 + 1) * HWn + rem] = od;
}

extern "C" void kernel_launch(void* const* d_in, const int* in_sizes, int n_in,
                              void* d_out, int out_size, void* d_ws, size_t ws_size,
                              hipStream_t stream) {
    const float* x     = (const float*)d_in[0];
    const float* we    = (const float*)d_in[1];
    const float* wd    = (const float*)d_in[2];
    const float* bn_ge = (const float*)d_in[3];
    const float* bn_gd = (const float*)d_in[5];
    const float* conve = (const float*)d_in[7];
    const float* convd = (const float*)d_in[8];
    const float* g_e   = (const float*)d_in[9];
    const float* b_e   = (const float*)d_in[10];
    const float* g_d   = (const float*)d_in[11];
    const float* b_d   = (const float*)d_in[12];
    float* ws = (float*)d_ws;
    unsigned* ef = (unsigned*)d_ws + WS_EF;

    // zero scal + ye + yd (contiguous at ws start)
    hipMemsetAsync(d_ws, 0, (size_t)(4 + 2 * N1) * sizeof(float), stream);
    hipLaunchKernelGGL(k_exp, dim3(512 * HWn / 256), dim3(256), 0, stream,
                       x, ef, we, wd, ws + WS_WG);
    hipLaunchKernelGGL(k_morph8, dim3(36, 64), dim3(256), 0, stream,
                       ef, ws + WS_WG, ws + WS_PART);
    hipLaunchKernelGGL(k_red, dim3(192), dim3(256), 0, stream, ws + WS_PART, ws + WS_SUM);
    hipLaunchKernelGGL(k_pass2, dim3(36, 64), dim3(256), 0, stream,
                       ef, ws + WS_WG, ws + WS_SUM, ws + WS_SQS,
                       bn_ge, bn_gd, conve, convd, ws + WS_YE, ws + WS_YD);
    hipLaunchKernelGGL(k_fstats, dim3(1152), dim3(256), 0, stream,
                       ws + WS_YE, ws + WS_YD, ws + WS_SCAL);
    hipLaunchKernelGGL(k_final, dim3(1152), dim3(256), 0, stream,
                       ws + WS_YE, ws + WS_YD, ws + WS_SCAL, g_e, b_e, g_d, b_d,
                       (float*)d_out);
}